// Round 2
// baseline (250.443 us; speedup 1.0000x reference)
//
#include <hip/hip_runtime.h>
#include <hip/hip_bf16.h>

// InputAttention: B=256, T=128, F=1024, H=512
//   c[b,t]  = b1[t] + h[b,:]·W1[t,128:640] + s[b,:]·W1[t,640:1152]   (kA_c, fp32)
//   u[f,b,t]= sum_k x[b,k,f]*W1[t,k] + c[b,t]                        (kB_e, bf16 MFMA)
//   e[b,f]  = b2 + sum_t W2[t]*tanh(u)                               (kB_e epilogue)
//   out[b,f]= softmax_f(e[b,:])                                      (kC)

#define B_N 256
#define T_N 128
#define F_N 1024
#define H_N 512
#define IN1 1152

typedef __bf16 bf16x8 __attribute__((ext_vector_type(8)));
typedef float f32x16 __attribute__((ext_vector_type(16)));
typedef float f32x4_t __attribute__((ext_vector_type(4)));

__device__ __forceinline__ float wave_reduce_sum(float v) {
#pragma unroll
  for (int off = 32; off >= 1; off >>= 1) v += __shfl_xor(v, off, 64);
  return v;
}
__device__ __forceinline__ float wave_reduce_max(float v) {
#pragma unroll
  for (int off = 32; off >= 1; off >>= 1) v = fmaxf(v, __shfl_xor(v, off, 64));
  return v;
}

__device__ __forceinline__ float tanh_fast(float u) {
  u = fminf(fmaxf(u, -15.f), 15.f);
  float e2 = __expf(2.f * u);
  return (e2 - 1.f) / (e2 + 1.f);
}

// ---------------- Kernel A: c[b,t] (fp32, exact) ----------------
// grid 128 = (bg 0..31)*4 + (tg 0..3); block = 8 b x 32 t, 256 thr, h/s staged in LDS.
#define HSP 1028  // padded pitch (floats) to break bank alignment
__global__ __launch_bounds__(256) void kA_c(const float* __restrict__ h,
                                            const float* __restrict__ s,
                                            const float* __restrict__ W1,
                                            const float* __restrict__ b1,
                                            float* __restrict__ c) {
  __shared__ __align__(16) float hs[8 * HSP];  // ~33 KB
  int tid = threadIdx.x;
  int bg = blockIdx.x >> 2;
  int tg = blockIdx.x & 3;
#pragma unroll
  for (int i = 0; i < 8; ++i) {
    int p = tid + 256 * i;  // float4 id over 8b x 256
    int bl = p >> 8;
    int j4 = p & 255;
    int b = bg * 8 + bl;
    float4 v;
    if (j4 < 128) v = reinterpret_cast<const float4*>(h + (size_t)b * H_N)[j4];
    else v = reinterpret_cast<const float4*>(s + (size_t)b * H_N)[j4 - 128];
    *reinterpret_cast<float4*>(&hs[bl * HSP + j4 * 4]) = v;
  }
  __syncthreads();
  int bl = tid >> 5, ti = tid & 31;
  int t = tg * 32 + ti;
  int b = bg * 8 + bl;
  const float4* wrow = reinterpret_cast<const float4*>(W1 + (size_t)t * IN1 + T_N);
  const float4* vrow = reinterpret_cast<const float4*>(&hs[bl * HSP]);
  float acc = 0.f;
#pragma unroll 4
  for (int j4 = 0; j4 < 256; ++j4) {
    float4 w = wrow[j4], v = vrow[j4];
    acc += w.x * v.x + w.y * v.y + w.z * v.z + w.w * v.w;
  }
  c[b * T_N + t] = acc + b1[t];
}

// ---------------- Kernel A2: pack W1[:, :128] into bf16 MFMA A-fragments ----------------
// frag position p = ((tt*8+kk)*64 + lane)*8 + j  holds  W1[tt*32+(lane&31)][kk*16+8*(lane>>5)+j]
__global__ __launch_bounds__(256) void kA_frag(const float* __restrict__ W1,
                                               unsigned short* __restrict__ w1frag) {
  int i = blockIdx.x * 256 + threadIdx.x;  // 0..8191, 2 elems each
  int p0 = i * 2;
  int j = p0 & 7;
  int lane = (p0 >> 3) & 63;
  int kk = (p0 >> 9) & 7;
  int tt = (p0 >> 12) & 3;
  int t = tt * 32 + (lane & 31);
  int k = kk * 16 + 8 * (lane >> 5) + j;
  const float2 w = *reinterpret_cast<const float2*>(W1 + t * IN1 + k);
  __bf16 a = (__bf16)w.x, bq = (__bf16)w.y;
  unsigned short ua = __builtin_bit_cast(unsigned short, a);
  unsigned short ub = __builtin_bit_cast(unsigned short, bq);
  *reinterpret_cast<unsigned*>(w1frag + p0) = (unsigned)ua | ((unsigned)ub << 16);
}

// ---------------- Kernel B: e[b,f] via MFMA + tanh reduction ----------------
// grid 2048 x 256 thr (4 waves). block = (b = bid>>3, fg = bid&7) covering f0 = fg*128 .. +128.
// Wave w owns t-tile t = w*32..w*32+32, ALL 128 f of the block via 4 q-chains:
//   lane l31 loads float4 x[b][k][f0 + 4*l31] -> B fragments q=0..3 map lane l31 -> f = f0+4*l31+q.
// A = W1tt fragments from LDS (1 ds_read_b128 per kk). t-partials combined across waves in LDS.
__global__ __launch_bounds__(256) void kB_e(const float* __restrict__ x,
                                            const unsigned short* __restrict__ w1frag,
                                            const float* __restrict__ c,
                                            const float* __restrict__ W2,
                                            const float* __restrict__ b2,
                                            float* __restrict__ e) {
  __shared__ __align__(16) unsigned short w1lds[16384];  // 32 KiB
  __shared__ __align__(16) float clds[T_N];
  __shared__ __align__(16) float w2lds[T_N];
  __shared__ __align__(16) float epart[4][T_N];  // per-wave t-partials
  int tid = threadIdx.x;
  int b = blockIdx.x >> 3;
  int fg = blockIdx.x & 7;

  {  // stage fragment-ordered W1tt
    const uint4* src = reinterpret_cast<const uint4*>(w1frag);
    uint4* dst = reinterpret_cast<uint4*>(w1lds);
#pragma unroll
    for (int i = 0; i < 8; ++i) dst[tid + 256 * i] = src[tid + 256 * i];
  }
  if (tid < T_N) clds[tid] = c[b * T_N + tid];
  else if (tid < 2 * T_N) w2lds[tid - T_N] = W2[tid - T_N];
  __syncthreads();

  int lane = tid & 63, wave = tid >> 6;
  int g = lane >> 5, l31 = lane & 31;
  int f0 = fg * 128;

  // float4 view of x[b][.][f0..f0+128); row stride = F_N/4 = 256 float4
  const float4* xb4 = reinterpret_cast<const float4*>(x + (size_t)b * T_N * F_N + f0);
  const bf16x8* af = reinterpret_cast<const bf16x8*>(w1lds);

  f32x16 acc0 = {}, acc1 = {}, acc2 = {}, acc3 = {};
#pragma unroll
  for (int kk = 0; kk < 8; ++kk) {
    float4 xq[8];
#pragma unroll
    for (int j = 0; j < 8; ++j)
      xq[j] = xb4[(size_t)(kk * 16 + 8 * g + j) * 256 + l31];
    bf16x8 bf0, bf1, bf2, bf3;
#pragma unroll
    for (int j = 0; j < 8; ++j) {
      bf0[j] = (__bf16)xq[j].x;
      bf1[j] = (__bf16)xq[j].y;
      bf2[j] = (__bf16)xq[j].z;
      bf3[j] = (__bf16)xq[j].w;
    }
    bf16x8 afr = af[wave * 512 + kk * 64 + lane];
    acc0 = __builtin_amdgcn_mfma_f32_32x32x16_bf16(afr, bf0, acc0, 0, 0, 0);
    acc1 = __builtin_amdgcn_mfma_f32_32x32x16_bf16(afr, bf1, acc1, 0, 0, 0);
    acc2 = __builtin_amdgcn_mfma_f32_32x32x16_bf16(afr, bf2, acc2, 0, 0, 0);
    acc3 = __builtin_amdgcn_mfma_f32_32x32x16_bf16(afr, bf3, acc3, 0, 0, 0);
  }

  // epilogue: C/D layout row = (reg&3) + 8*(reg>>2) + 4*g, col = l31.
  // Chain q's column l31 corresponds to f = f0 + 4*l31 + q.
  int tbase = wave * 32 + 4 * g;
  float4 es = {0.f, 0.f, 0.f, 0.f};
#pragma unroll
  for (int q = 0; q < 4; ++q) {  // q = reg>>2 (row-group)
    f32x4_t cq = *reinterpret_cast<const f32x4_t*>(&clds[tbase + 8 * q]);
    f32x4_t wq = *reinterpret_cast<const f32x4_t*>(&w2lds[tbase + 8 * q]);
#pragma unroll
    for (int r = 0; r < 4; ++r) {
      int reg = q * 4 + r;
      float w2v = wq[r], cv = cq[r];
      es.x += w2v * tanh_fast(acc0[reg] + cv);
      es.y += w2v * tanh_fast(acc1[reg] + cv);
      es.z += w2v * tanh_fast(acc2[reg] + cv);
      es.w += w2v * tanh_fast(acc3[reg] + cv);
    }
  }
  // combine the two g-halves (same f, complementary t-rows)
  es.x += __shfl_xor(es.x, 32, 64);
  es.y += __shfl_xor(es.y, 32, 64);
  es.z += __shfl_xor(es.z, 32, 64);
  es.w += __shfl_xor(es.w, 32, 64);
  if (g == 0) *reinterpret_cast<float4*>(&epart[wave][4 * l31]) = es;
  __syncthreads();
  if (tid < T_N) {
    float sum = epart[0][tid] + epart[1][tid] + epart[2][tid] + epart[3][tid] + b2[0];
    e[(size_t)b * F_N + f0 + tid] = sum;
  }
}

// ---------------- Kernel C: softmax over f per b, in-place on d_out ----------------
__global__ __launch_bounds__(256) void kC_softmax(float* __restrict__ out) {
  int b = blockIdx.x, tid = threadIdx.x;
  int lane = tid & 63, wid = tid >> 6;
  float* row = out + (size_t)b * F_N;
  float v[4];
#pragma unroll
  for (int q = 0; q < 4; ++q) v[q] = row[tid + 256 * q];
  float m = fmaxf(fmaxf(v[0], v[1]), fmaxf(v[2], v[3]));
  m = wave_reduce_max(m);
  __shared__ float rm[4], rs[4];
  if (lane == 0) rm[wid] = m;
  __syncthreads();
  float M = fmaxf(fmaxf(rm[0], rm[1]), fmaxf(rm[2], rm[3]));
  float ssum = 0.f;
#pragma unroll
  for (int q = 0; q < 4; ++q) {
    v[q] = __expf(v[q] - M);
    ssum += v[q];
  }
  ssum = wave_reduce_sum(ssum);
  if (lane == 0) rs[wid] = ssum;
  __syncthreads();
  float S = rs[0] + rs[1] + rs[2] + rs[3];
  float inv = 1.f / S;
#pragma unroll
  for (int q = 0; q < 4; ++q) row[tid + 256 * q] = v[q] * inv;
}

extern "C" void kernel_launch(void* const* d_in, const int* in_sizes, int n_in,
                              void* d_out, int out_size, void* d_ws, size_t ws_size,
                              hipStream_t stream) {
  const float* h = (const float*)d_in[0];
  const float* s = (const float*)d_in[1];
  const float* x = (const float*)d_in[2];
  const float* W1 = (const float*)d_in[3];
  const float* b1 = (const float*)d_in[4];
  const float* W2 = (const float*)d_in[5];
  const float* b2 = (const float*)d_in[6];
  float* out = (float*)d_out;

  float* c_ws = (float*)d_ws;                                               // 128 KiB
  unsigned short* w1frag = (unsigned short*)((char*)d_ws + B_N * T_N * 4);  // 32 KiB

  kA_c<<<128, 256, 0, stream>>>(h, s, W1, b1, c_ws);
  kA_frag<<<32, 256, 0, stream>>>(W1, w1frag);
  kB_e<<<2048, 256, 0, stream>>>(x, w1frag, c_ws, W2, b2, out);
  kC_softmax<<<256, 256, 0, stream>>>(out);
}